// Round 3
// baseline (606.452 us; speedup 1.0000x reference)
//
#include <hip/hip_runtime.h>

// SamClip: N=1024 binary masks (256x256 fp32), scores[1024].
// out int32: [0:1024] = order (argsort desc, stable), [1024:2048] = keep (0/1).
//
// R3: 128x128 triangular tiles, 8x8 register tile per thread (2x LDS reuse vs R2),
// KQ=16 k-split for load balance, XOR-swizzled LDS, combine with (36,16) grid.

#define N_MASKS 1024
#define HW 65536
#define WPR 2048          // u32 words per packed row
#define NT 8              // 8x8 grid of 128-row tiles
#define NPAIRS 36         // NT*(NT+1)/2
#define KQ 16             // k-split: each pair block does 2 chunks of 64 words

__device__ __forceinline__ void tile_from_pair(int p, int& I, int& J) {
    int rem = p, i = 0;
    while (rem >= NT - i) { rem -= NT - i; ++i; }
    I = i; J = i + rem;
}

// ---------------- Kernel A: stable descending argsort + init ----------------
__global__ __launch_bounds__(128) void sort_kernel(const float* __restrict__ scores,
                                                   int* __restrict__ order,
                                                   float* __restrict__ ssort,
                                                   int* __restrict__ out_order,
                                                   float* __restrict__ area,
                                                   unsigned* __restrict__ ioumax,
                                                   unsigned* __restrict__ innu,
                                                   unsigned* __restrict__ innl) {
    __shared__ float s[N_MASKS];
    const int t = threadIdx.x;
    for (int k = t; k < N_MASKS; k += 128) s[k] = scores[k];
    __syncthreads();
    const int i = blockIdx.x * 128 + t;
    const float si = s[i];
    int rank = 0;
    #pragma unroll 8
    for (int j = 0; j < N_MASKS; ++j) {
        const float sj = s[j];
        rank += (int)((sj > si) || (sj == si && j < i));
    }
    order[rank] = i;
    ssort[rank] = si;
    out_order[rank] = i;
    area[i] = 0.0f;
    ioumax[i] = 0u; innu[i] = 0u; innl[i] = 0u;
}

// ---------------- Kernel B: bitpack (sorted order) + area ----------------
__global__ __launch_bounds__(256) void pack_kernel(const float* __restrict__ masks,
                                                   const int* __restrict__ order,
                                                   unsigned* __restrict__ packed,
                                                   float* __restrict__ area) {
    const int b = blockIdx.x;
    const int r = b >> 1, half = b & 1;
    const int src = order[r];
    const float4* __restrict__ row = (const float4*)(masks + (size_t)src * HW) + half * 8192;
    unsigned* __restrict__ prow = packed + (size_t)r * WPR + half * 1024;
    const int t = threadIdx.x;
    int cnt = 0;
    #pragma unroll
    for (int g = 0; g < 4; ++g) {
        unsigned bits = 0u;
        #pragma unroll
        for (int k = 0; k < 8; ++k) {
            const float4 f = row[g * 2048 + k * 256 + t];
            unsigned nib = (unsigned)(f.x != 0.0f)
                         | ((unsigned)(f.y != 0.0f) << 1)
                         | ((unsigned)(f.z != 0.0f) << 2)
                         | ((unsigned)(f.w != 0.0f) << 3);
            bits |= nib << (k * 4);
        }
        prow[g * 256 + t] = bits;
        cnt += __builtin_popcount(bits);
    }
    for (int off = 32; off > 0; off >>= 1) cnt += __shfl_down(cnt, off, 64);
    __shared__ int red[4];
    const int lane = t & 63, w = t >> 6;
    if (lane == 0) red[w] = cnt;
    __syncthreads();
    if (t == 0) atomicAdd(area + r, (float)(red[0] + red[1] + red[2] + red[3]));
}

// ---------------- Kernel C: pairwise popcount partials ----------------
// Block (p, kq): triangular 128x128 tile pair p (I<=J), 2 chunks of 64 words.
// LDS swizzle: logical (row, 16B-chunk c16) at physical chunk c16 ^ (row>>3).
// b-fragment reads hit 16 distinct chunks (conflict-free); a-side is a
// 4-address broadcast.
__global__ __launch_bounds__(256, 2) void pair_kernel(const unsigned* __restrict__ packed,
                                                      unsigned* __restrict__ partial) {
    __shared__ __align__(16) unsigned lA[128 * 64];
    __shared__ __align__(16) unsigned lB[128 * 64];

    const int p = blockIdx.x, kq = blockIdx.y;
    int I, J; tile_from_pair(p, I, J);
    const int A0 = I * 128, B0 = J * 128;
    const int t = threadIdx.x;
    const int tx = t & 15, ty = t >> 4;

    unsigned acc[8][8] = {};

    const int c0 = kq * 2;
    for (int c = c0; c < c0 + 2; ++c) {
        __syncthreads();
        #pragma unroll
        for (int it = 0; it < 8; ++it) {
            const int linear = it * 256 + t;          // uint4 index within chunk
            const int row = linear >> 4, c16 = linear & 15;
            const int phys = row * 64 + ((c16 ^ (row >> 3)) << 2);
            const uint4 va = *(const uint4*)(packed + (size_t)(A0 + row) * WPR + c * 64 + c16 * 4);
            const uint4 vb = *(const uint4*)(packed + (size_t)(B0 + row) * WPR + c * 64 + c16 * 4);
            *(uint4*)(lA + phys) = va;
            *(uint4*)(lB + phys) = vb;
        }
        __syncthreads();
        #pragma unroll
        for (int g = 0; g < 16; ++g) {
            uint4 a[8], b[8];
            #pragma unroll
            for (int i = 0; i < 8; ++i)
                a[i] = *(const uint4*)(lA + (ty * 8 + i) * 64 + ((g ^ ty) << 2));
            #pragma unroll
            for (int j = 0; j < 8; ++j)
                b[j] = *(const uint4*)(lB + (tx * 8 + j) * 64 + ((g ^ tx) << 2));
            #pragma unroll
            for (int i = 0; i < 8; ++i)
                #pragma unroll
                for (int j = 0; j < 8; ++j) {
                    acc[i][j] += __builtin_popcount(a[i].x & b[j].x);
                    acc[i][j] += __builtin_popcount(a[i].y & b[j].y);
                    acc[i][j] += __builtin_popcount(a[i].z & b[j].z);
                    acc[i][j] += __builtin_popcount(a[i].w & b[j].w);
                }
        }
    }

    unsigned* __restrict__ out = partial + ((size_t)kq * NPAIRS + p) * (128 * 128);
    #pragma unroll
    for (int i = 0; i < 8; ++i) {
        uint4 v0 = make_uint4(acc[i][0], acc[i][1], acc[i][2], acc[i][3]);
        uint4 v1 = make_uint4(acc[i][4], acc[i][5], acc[i][6], acc[i][7]);
        *(uint4*)(out + (ty * 8 + i) * 128 + tx * 8) = v0;
        *(uint4*)(out + (ty * 8 + i) * 128 + tx * 8 + 4) = v1;
    }
}

// ---------------- Kernel D: combine partials + epilogue + column max ----------------
// Grid (NPAIRS, 16): block handles 8 rows x 128 cols of tile p.
__global__ __launch_bounds__(256) void combine_kernel(const unsigned* __restrict__ partial,
                                                      const float* __restrict__ area,
                                                      unsigned* __restrict__ ioumax,
                                                      unsigned* __restrict__ innu,
                                                      unsigned* __restrict__ innl) {
    __shared__ unsigned redI[128], redU[128], redLB[128], redLA[8];
    __shared__ float aB[128];

    const int p = blockIdx.x, rg = blockIdx.y;
    int I, J; tile_from_pair(p, I, J);
    const int A0 = I * 128, B0 = J * 128;
    const int t = threadIdx.x;
    if (t < 128) { redI[t] = 0u; redU[t] = 0u; redLB[t] = 0u; aB[t] = area[B0 + t]; }
    if (t < 8) redLA[t] = 0u;
    __syncthreads();

    const int row = rg * 8 + (t >> 5);
    const int col = (t & 31) * 4;
    const int a = A0 + row;
    const float fa = area[a];

    unsigned sx = 0, sy = 0, sz = 0, sw = 0;
    #pragma unroll
    for (int kq = 0; kq < KQ; ++kq) {
        const uint4 v = *(const uint4*)(partial + ((size_t)kq * NPAIRS + p) * 16384 + row * 128 + col);
        sx += v.x; sy += v.y; sz += v.z; sw += v.w;
    }
    const unsigned sums[4] = { sx, sy, sz, sw };

    float mLA = 0.0f;
    #pragma unroll
    for (int j = 0; j < 4; ++j) {
        const int b = B0 + col + j;
        if (a > b) continue;
        const float inter = (float)sums[j];
        const float fb = aB[col + j];
        const float uni = (fb + fa) - inter;
        const float iou = inter / (uni + 1e-8f);
        const float ra = inter / (fa + 1e-8f);   // ratio_i (row a)
        const float rb = inter / (fb + 1e-8f);   // ratio_j (col b)
        const float v = __fsub_rn(1.0f, __fmul_rn(rb, ra));
        const float iab = (ra < 0.5f && rb >= 0.85f) ? v : 0.0f;
        const float iba = (rb < 0.5f && ra >= 0.85f) ? v : 0.0f;
        if (a < b) {
            atomicMax(&redI[col + j], __float_as_uint(iou));
            atomicMax(&redU[col + j], __float_as_uint(iab));   // inner[a,b] -> innu[b]
            mLA = fmaxf(mLA, iba);                             // inner[b,a] -> innl[a]
        }
        if (a == b - 1) atomicMax(&redLB[col + j], __float_as_uint(iab)); // superdiag -> innl[b]
    }
    atomicMax(&redLA[t >> 5], __float_as_uint(mLA));
    __syncthreads();
    if (t < 128) {
        atomicMax(&ioumax[B0 + t], redI[t]);
        atomicMax(&innu[B0 + t], redU[t]);
        atomicMax(&innl[B0 + t], redLB[t]);
    }
    if (t < 8) atomicMax(&innl[A0 + rg * 8 + t], redLA[t]);
}

// ---------------- Kernel E: final keep ----------------
__global__ __launch_bounds__(256) void keep_kernel(const float* __restrict__ ssort,
                                                   const unsigned* __restrict__ ioumax,
                                                   const unsigned* __restrict__ innu,
                                                   const unsigned* __restrict__ innl,
                                                   int* __restrict__ out_keep) {
    const int r = blockIdx.x * 256 + threadIdx.x;
    const float s0 = ssort[0];
    const bool conf = (s0 > 0.7f) ? (ssort[r] > 0.7f) : (r < 3);
    const bool keep = (__uint_as_float(ioumax[r]) <= 0.8f) && conf &&
                      (__uint_as_float(innu[r]) <= 0.5f) &&
                      (__uint_as_float(innl[r]) <= 0.5f);
    out_keep[r] = keep ? 1 : 0;
}

extern "C" void kernel_launch(void* const* d_in, const int* in_sizes, int n_in,
                              void* d_out, int out_size, void* d_ws, size_t ws_size,
                              hipStream_t stream) {
    const float* masks  = (const float*)d_in[0];
    const float* scores = (const float*)d_in[1];
    int* out = (int*)d_out;

    unsigned* packed  = (unsigned*)d_ws;                       // 8 MB
    unsigned* partial = packed + (size_t)N_MASKS * WPR;        // 16*36*16384 u32 = 37.75 MB
    unsigned* tail    = partial + (size_t)KQ * NPAIRS * 16384;
    int*      order   = (int*)tail;
    float*    ssort   = (float*)(order + N_MASKS);
    float*    area    = (float*)(ssort + N_MASKS);
    unsigned* ioumax  = (unsigned*)(area + N_MASKS);
    unsigned* innu    = ioumax + N_MASKS;
    unsigned* innl    = innu + N_MASKS;

    sort_kernel<<<8, 128, 0, stream>>>(scores, order, ssort, out, area, ioumax, innu, innl);
    pack_kernel<<<2048, 256, 0, stream>>>(masks, order, packed, area);
    pair_kernel<<<dim3(NPAIRS, KQ), 256, 0, stream>>>(packed, partial);
    combine_kernel<<<dim3(NPAIRS, 16), 256, 0, stream>>>(partial, area, ioumax, innu, innl);
    keep_kernel<<<4, 256, 0, stream>>>(ssort, ioumax, innu, innl, out + N_MASKS);
}

// Round 4
// 544.636 us; speedup vs baseline: 1.1135x; 1.1135x over previous
//
#include <hip/hip_runtime.h>

// SamClip: N=1024 binary masks (256x256 fp32), scores[1024].
// out int32: [0:1024] = order (argsort desc, stable), [1024:2048] = keep (0/1).
//
// R4: 128x128 triangular tiles, 8x8 register tile, KQ=32 (one 64-word chunk
// per block, single barrier), no register-count clamp (R3's launch_bounds(,2)
// forced 128 VGPRs -> acc spills -> 215MB scratch writes). b-fragments
// consumed in batches of 4 to keep peak pressure ~140 regs.

#define N_MASKS 1024
#define HW 65536
#define WPR 2048          // u32 words per packed row
#define NT 8              // 8x8 grid of 128-row tiles
#define NPAIRS 36         // NT*(NT+1)/2
#define KQ 32             // k-split: each pair block does 1 chunk of 64 words

__device__ __forceinline__ void tile_from_pair(int p, int& I, int& J) {
    int rem = p, i = 0;
    while (rem >= NT - i) { rem -= NT - i; ++i; }
    I = i; J = i + rem;
}

// ---------------- Kernel A: stable descending argsort + init ----------------
__global__ __launch_bounds__(128) void sort_kernel(const float* __restrict__ scores,
                                                   int* __restrict__ order,
                                                   float* __restrict__ ssort,
                                                   int* __restrict__ out_order,
                                                   float* __restrict__ area,
                                                   unsigned* __restrict__ ioumax,
                                                   unsigned* __restrict__ innu,
                                                   unsigned* __restrict__ innl) {
    __shared__ float s[N_MASKS];
    const int t = threadIdx.x;
    for (int k = t; k < N_MASKS; k += 128) s[k] = scores[k];
    __syncthreads();
    const int i = blockIdx.x * 128 + t;
    const float si = s[i];
    int rank = 0;
    #pragma unroll 8
    for (int j = 0; j < N_MASKS; ++j) {
        const float sj = s[j];
        rank += (int)((sj > si) || (sj == si && j < i));
    }
    order[rank] = i;
    ssort[rank] = si;
    out_order[rank] = i;
    area[i] = 0.0f;
    ioumax[i] = 0u; innu[i] = 0u; innl[i] = 0u;
}

// ---------------- Kernel B: bitpack (sorted order) + area ----------------
__global__ __launch_bounds__(256) void pack_kernel(const float* __restrict__ masks,
                                                   const int* __restrict__ order,
                                                   unsigned* __restrict__ packed,
                                                   float* __restrict__ area) {
    const int b = blockIdx.x;
    const int r = b >> 1, half = b & 1;
    const int src = order[r];
    const float4* __restrict__ row = (const float4*)(masks + (size_t)src * HW) + half * 8192;
    unsigned* __restrict__ prow = packed + (size_t)r * WPR + half * 1024;
    const int t = threadIdx.x;
    int cnt = 0;
    #pragma unroll
    for (int g = 0; g < 4; ++g) {
        unsigned bits = 0u;
        #pragma unroll
        for (int k = 0; k < 8; ++k) {
            const float4 f = row[g * 2048 + k * 256 + t];
            unsigned nib = (unsigned)(f.x != 0.0f)
                         | ((unsigned)(f.y != 0.0f) << 1)
                         | ((unsigned)(f.z != 0.0f) << 2)
                         | ((unsigned)(f.w != 0.0f) << 3);
            bits |= nib << (k * 4);
        }
        prow[g * 256 + t] = bits;
        cnt += __builtin_popcount(bits);
    }
    for (int off = 32; off > 0; off >>= 1) cnt += __shfl_down(cnt, off, 64);
    __shared__ int red[4];
    const int lane = t & 63, w = t >> 6;
    if (lane == 0) red[w] = cnt;
    __syncthreads();
    if (t == 0) atomicAdd(area + r, (float)(red[0] + red[1] + red[2] + red[3]));
}

// ---------------- Kernel C: pairwise popcount partials ----------------
// Block (p, kq): triangular 128x128 tile pair p (I<=J), one 64-word chunk.
// LDS swizzle: logical (row, 16B-chunk c16) at physical chunk c16 ^ (row>>3):
// b-fragment reads hit 16 distinct chunks across tx (conflict-free), a-side
// is a 4-address broadcast. Stage once, one barrier, 16 g-groups.
__global__ __launch_bounds__(256) void pair_kernel(const unsigned* __restrict__ packed,
                                                   unsigned* __restrict__ partial) {
    __shared__ __align__(16) unsigned lA[128 * 64];
    __shared__ __align__(16) unsigned lB[128 * 64];

    const int p = blockIdx.x, kq = blockIdx.y;
    int I, J; tile_from_pair(p, I, J);
    const int A0 = I * 128, B0 = J * 128;
    const int t = threadIdx.x;
    const int tx = t & 15, ty = t >> 4;

    // stage chunk kq: 128 rows x 64 words per side
    #pragma unroll
    for (int it = 0; it < 8; ++it) {
        const int linear = it * 256 + t;          // uint4 index within chunk
        const int row = linear >> 4, c16 = linear & 15;
        const int phys = row * 64 + ((c16 ^ (row >> 3)) << 2);
        const uint4 va = *(const uint4*)(packed + (size_t)(A0 + row) * WPR + kq * 64 + c16 * 4);
        const uint4 vb = *(const uint4*)(packed + (size_t)(B0 + row) * WPR + kq * 64 + c16 * 4);
        *(uint4*)(lA + phys) = va;
        *(uint4*)(lB + phys) = vb;
    }
    __syncthreads();

    unsigned acc[8][8] = {};
    #pragma unroll
    for (int g = 0; g < 16; ++g) {
        uint4 a[8];
        #pragma unroll
        for (int i = 0; i < 8; ++i)
            a[i] = *(const uint4*)(lA + (ty * 8 + i) * 64 + ((g ^ ty) << 2));
        #pragma unroll
        for (int jb = 0; jb < 2; ++jb) {          // b in batches of 4: peak regs ~140
            uint4 b[4];
            #pragma unroll
            for (int j = 0; j < 4; ++j)
                b[j] = *(const uint4*)(lB + (tx * 8 + jb * 4 + j) * 64 + ((g ^ tx) << 2));
            #pragma unroll
            for (int i = 0; i < 8; ++i)
                #pragma unroll
                for (int j = 0; j < 4; ++j) {
                    unsigned s = acc[i][jb * 4 + j];
                    s += __builtin_popcount(a[i].x & b[j].x);
                    s += __builtin_popcount(a[i].y & b[j].y);
                    s += __builtin_popcount(a[i].z & b[j].z);
                    s += __builtin_popcount(a[i].w & b[j].w);
                    acc[i][jb * 4 + j] = s;
                }
        }
    }

    unsigned* __restrict__ out = partial + ((size_t)kq * NPAIRS + p) * (128 * 128);
    #pragma unroll
    for (int i = 0; i < 8; ++i) {
        uint4 v0 = make_uint4(acc[i][0], acc[i][1], acc[i][2], acc[i][3]);
        uint4 v1 = make_uint4(acc[i][4], acc[i][5], acc[i][6], acc[i][7]);
        *(uint4*)(out + (ty * 8 + i) * 128 + tx * 8) = v0;
        *(uint4*)(out + (ty * 8 + i) * 128 + tx * 8 + 4) = v1;
    }
}

// ---------------- Kernel D: combine partials + epilogue + column max ----------------
// Grid (NPAIRS, 16): block handles 8 rows x 128 cols of tile p.
__global__ __launch_bounds__(256) void combine_kernel(const unsigned* __restrict__ partial,
                                                      const float* __restrict__ area,
                                                      unsigned* __restrict__ ioumax,
                                                      unsigned* __restrict__ innu,
                                                      unsigned* __restrict__ innl) {
    __shared__ unsigned redI[128], redU[128], redLB[128], redLA[8];
    __shared__ float aB[128];

    const int p = blockIdx.x, rg = blockIdx.y;
    int I, J; tile_from_pair(p, I, J);
    const int A0 = I * 128, B0 = J * 128;
    const int t = threadIdx.x;
    if (t < 128) { redI[t] = 0u; redU[t] = 0u; redLB[t] = 0u; aB[t] = area[B0 + t]; }
    if (t < 8) redLA[t] = 0u;
    __syncthreads();

    const int row = rg * 8 + (t >> 5);
    const int col = (t & 31) * 4;
    const int a = A0 + row;
    const float fa = area[a];

    unsigned sx = 0, sy = 0, sz = 0, sw = 0;
    #pragma unroll
    for (int kq = 0; kq < KQ; ++kq) {
        const uint4 v = *(const uint4*)(partial + ((size_t)kq * NPAIRS + p) * 16384 + row * 128 + col);
        sx += v.x; sy += v.y; sz += v.z; sw += v.w;
    }
    const unsigned sums[4] = { sx, sy, sz, sw };

    float mLA = 0.0f;
    #pragma unroll
    for (int j = 0; j < 4; ++j) {
        const int b = B0 + col + j;
        if (a > b) continue;
        const float inter = (float)sums[j];
        const float fb = aB[col + j];
        const float uni = (fb + fa) - inter;
        const float iou = inter / (uni + 1e-8f);
        const float ra = inter / (fa + 1e-8f);   // ratio_i (row a)
        const float rb = inter / (fb + 1e-8f);   // ratio_j (col b)
        const float v = __fsub_rn(1.0f, __fmul_rn(rb, ra));
        const float iab = (ra < 0.5f && rb >= 0.85f) ? v : 0.0f;
        const float iba = (rb < 0.5f && ra >= 0.85f) ? v : 0.0f;
        if (a < b) {
            atomicMax(&redI[col + j], __float_as_uint(iou));
            atomicMax(&redU[col + j], __float_as_uint(iab));   // inner[a,b] -> innu[b]
            mLA = fmaxf(mLA, iba);                             // inner[b,a] -> innl[a]
        }
        if (a == b - 1) atomicMax(&redLB[col + j], __float_as_uint(iab)); // superdiag -> innl[b]
    }
    atomicMax(&redLA[t >> 5], __float_as_uint(mLA));
    __syncthreads();
    if (t < 128) {
        atomicMax(&ioumax[B0 + t], redI[t]);
        atomicMax(&innu[B0 + t], redU[t]);
        atomicMax(&innl[B0 + t], redLB[t]);
    }
    if (t < 8) atomicMax(&innl[A0 + rg * 8 + t], redLA[t]);
}

// ---------------- Kernel E: final keep ----------------
__global__ __launch_bounds__(256) void keep_kernel(const float* __restrict__ ssort,
                                                   const unsigned* __restrict__ ioumax,
                                                   const unsigned* __restrict__ innu,
                                                   const unsigned* __restrict__ innl,
                                                   int* __restrict__ out_keep) {
    const int r = blockIdx.x * 256 + threadIdx.x;
    const float s0 = ssort[0];
    const bool conf = (s0 > 0.7f) ? (ssort[r] > 0.7f) : (r < 3);
    const bool keep = (__uint_as_float(ioumax[r]) <= 0.8f) && conf &&
                      (__uint_as_float(innu[r]) <= 0.5f) &&
                      (__uint_as_float(innl[r]) <= 0.5f);
    out_keep[r] = keep ? 1 : 0;
}

extern "C" void kernel_launch(void* const* d_in, const int* in_sizes, int n_in,
                              void* d_out, int out_size, void* d_ws, size_t ws_size,
                              hipStream_t stream) {
    const float* masks  = (const float*)d_in[0];
    const float* scores = (const float*)d_in[1];
    int* out = (int*)d_out;

    unsigned* packed  = (unsigned*)d_ws;                       // 8 MB
    unsigned* partial = packed + (size_t)N_MASKS * WPR;        // 32*36*16384 u32 = 75.5 MB
    unsigned* tail    = partial + (size_t)KQ * NPAIRS * 16384;
    int*      order   = (int*)tail;
    float*    ssort   = (float*)(order + N_MASKS);
    float*    area    = (float*)(ssort + N_MASKS);
    unsigned* ioumax  = (unsigned*)(area + N_MASKS);
    unsigned* innu    = ioumax + N_MASKS;
    unsigned* innl    = innu + N_MASKS;

    sort_kernel<<<8, 128, 0, stream>>>(scores, order, ssort, out, area, ioumax, innu, innl);
    pack_kernel<<<2048, 256, 0, stream>>>(masks, order, packed, area);
    pair_kernel<<<dim3(NPAIRS, KQ), 256, 0, stream>>>(packed, partial);
    combine_kernel<<<dim3(NPAIRS, 16), 256, 0, stream>>>(partial, area, ioumax, innu, innl);
    keep_kernel<<<4, 256, 0, stream>>>(ssort, ioumax, innu, innl, out + N_MASKS);
}

// Round 5
// 543.608 us; speedup vs baseline: 1.1156x; 1.0019x over previous
//
#include <hip/hip_runtime.h>

// SamClip: N=1024 binary masks (256x256 fp32), scores[1024].
// out int32: [0:1024] = order (argsort desc, stable), [1024:2048] = keep (0/1).
//
// R5: pair kernel rebuilt to be spill-proof: 128x64 tiles (48 KB LDS,
// 3 blocks/CU), 8x4 thread tile (acc 32 + a 32 + b 16 ~ 100 VGPRs),
// __launch_bounds__(256,3) caps at 170 VGPRs (>> demand, so no forced spill).
// 72 triangular (128-row x 64-col) tile pairs (J >= 2I), KQ=16, one barrier.

#define N_MASKS 1024
#define HW 65536
#define WPR 2048          // u32 words per packed row
#define NPAIRS 72         // (I,J): I in [0,8), J in [2I,16)
#define KQ 16             // k-split: each pair block does 1 chunk of 64 words

__device__ __forceinline__ void tile_from_pair(int p, int& I, int& J) {
    int rem = p, i = 0;
    while (rem >= 16 - 2 * i) { rem -= 16 - 2 * i; ++i; }
    I = i; J = 2 * i + rem;
}

// ---------------- Kernel A: stable descending argsort + init ----------------
__global__ __launch_bounds__(128) void sort_kernel(const float* __restrict__ scores,
                                                   int* __restrict__ order,
                                                   float* __restrict__ ssort,
                                                   int* __restrict__ out_order,
                                                   float* __restrict__ area,
                                                   unsigned* __restrict__ ioumax,
                                                   unsigned* __restrict__ innu,
                                                   unsigned* __restrict__ innl) {
    __shared__ float s[N_MASKS];
    const int t = threadIdx.x;
    for (int k = t; k < N_MASKS; k += 128) s[k] = scores[k];
    __syncthreads();
    const int i = blockIdx.x * 128 + t;
    const float si = s[i];
    int rank = 0;
    #pragma unroll 8
    for (int j = 0; j < N_MASKS; ++j) {
        const float sj = s[j];
        rank += (int)((sj > si) || (sj == si && j < i));
    }
    order[rank] = i;
    ssort[rank] = si;
    out_order[rank] = i;
    area[i] = 0.0f;
    ioumax[i] = 0u; innu[i] = 0u; innl[i] = 0u;
}

// ---------------- Kernel B: bitpack (sorted order) + area ----------------
__global__ __launch_bounds__(256) void pack_kernel(const float* __restrict__ masks,
                                                   const int* __restrict__ order,
                                                   unsigned* __restrict__ packed,
                                                   float* __restrict__ area) {
    const int b = blockIdx.x;
    const int r = b >> 1, half = b & 1;
    const int src = order[r];
    const float4* __restrict__ row = (const float4*)(masks + (size_t)src * HW) + half * 8192;
    unsigned* __restrict__ prow = packed + (size_t)r * WPR + half * 1024;
    const int t = threadIdx.x;
    int cnt = 0;
    #pragma unroll
    for (int g = 0; g < 4; ++g) {
        unsigned bits = 0u;
        #pragma unroll
        for (int k = 0; k < 8; ++k) {
            const float4 f = row[g * 2048 + k * 256 + t];
            unsigned nib = (unsigned)(f.x != 0.0f)
                         | ((unsigned)(f.y != 0.0f) << 1)
                         | ((unsigned)(f.z != 0.0f) << 2)
                         | ((unsigned)(f.w != 0.0f) << 3);
            bits |= nib << (k * 4);
        }
        prow[g * 256 + t] = bits;
        cnt += __builtin_popcount(bits);
    }
    for (int off = 32; off > 0; off >>= 1) cnt += __shfl_down(cnt, off, 64);
    __shared__ int red[4];
    const int lane = t & 63, w = t >> 6;
    if (lane == 0) red[w] = cnt;
    __syncthreads();
    if (t == 0) atomicAdd(area + r, (float)(red[0] + red[1] + red[2] + red[3]));
}

// ---------------- Kernel C: pairwise popcount partials ----------------
// Block (p, kq): tile pair p = (I: rows 128I.., J: cols 64J..), one 64-word
// chunk. LDS swizzle: logical (row, 16B-chunk c16) stored at physical chunk
// c16 ^ (row>>3). a-reads: 4 distinct bank-quads/wave (broadcast); b-reads:
// 2 addresses/bank-quad (2-way = free, m136). Stage once, one barrier.
__global__ __launch_bounds__(256, 3) void pair_kernel(const unsigned* __restrict__ packed,
                                                      unsigned* __restrict__ partial) {
    __shared__ __align__(16) unsigned lA[128 * 64];   // 32 KB
    __shared__ __align__(16) unsigned lB[64 * 64];    // 16 KB

    const int p = blockIdx.x, kq = blockIdx.y;
    int I, J; tile_from_pair(p, I, J);
    const int A0 = I * 128, B0 = J * 64;
    const int t = threadIdx.x;
    const int tx = t & 15, ty = t >> 4;

    // stage A: 128 rows x 64 words (2048 uint4), B: 64 rows x 64 words (1024)
    #pragma unroll
    for (int it = 0; it < 8; ++it) {
        const int linear = it * 256 + t;
        const int row = linear >> 4, c16 = linear & 15;
        const int phys = row * 64 + ((c16 ^ (row >> 3)) << 2);
        const uint4 va = *(const uint4*)(packed + (size_t)(A0 + row) * WPR + kq * 64 + c16 * 4);
        *(uint4*)(lA + phys) = va;
        if (it < 4) {
            const uint4 vb = *(const uint4*)(packed + (size_t)(B0 + row) * WPR + kq * 64 + c16 * 4);
            *(uint4*)(lB + phys) = vb;
        }
    }
    __syncthreads();

    unsigned acc[8][4] = {};
    #pragma unroll
    for (int g = 0; g < 16; ++g) {
        uint4 a[8], b[4];
        #pragma unroll
        for (int i = 0; i < 8; ++i)
            a[i] = *(const uint4*)(lA + (ty * 8 + i) * 64 + ((g ^ ty) << 2));
        #pragma unroll
        for (int j = 0; j < 4; ++j) {
            const int brow = tx * 4 + j;
            b[j] = *(const uint4*)(lB + brow * 64 + ((g ^ (brow >> 3)) << 2));
        }
        #pragma unroll
        for (int i = 0; i < 8; ++i)
            #pragma unroll
            for (int j = 0; j < 4; ++j) {
                unsigned s = acc[i][j];
                s += __builtin_popcount(a[i].x & b[j].x);
                s += __builtin_popcount(a[i].y & b[j].y);
                s += __builtin_popcount(a[i].z & b[j].z);
                s += __builtin_popcount(a[i].w & b[j].w);
                acc[i][j] = s;
            }
    }

    // tile partial: 128 rows x 64 cols
    unsigned* __restrict__ out = partial + ((size_t)kq * NPAIRS + p) * (128 * 64);
    #pragma unroll
    for (int i = 0; i < 8; ++i) {
        uint4 v = make_uint4(acc[i][0], acc[i][1], acc[i][2], acc[i][3]);
        *(uint4*)(out + (ty * 8 + i) * 64 + tx * 4) = v;
    }
}

// ---------------- Kernel D: combine partials + epilogue + column max ----------------
// Grid (NPAIRS, 8): block handles 16 rows x 64 cols of tile p.
__global__ __launch_bounds__(256) void combine_kernel(const unsigned* __restrict__ partial,
                                                      const float* __restrict__ area,
                                                      unsigned* __restrict__ ioumax,
                                                      unsigned* __restrict__ innu,
                                                      unsigned* __restrict__ innl) {
    __shared__ unsigned redI[64], redU[64], redLB[64], redLA[16];
    __shared__ float aB[64];

    const int p = blockIdx.x, rg = blockIdx.y;
    int I, J; tile_from_pair(p, I, J);
    const int A0 = I * 128, B0 = J * 64;
    const int t = threadIdx.x;
    if (t < 64) { redI[t] = 0u; redU[t] = 0u; redLB[t] = 0u; aB[t] = area[B0 + t]; }
    if (t < 16) redLA[t] = 0u;
    __syncthreads();

    const int row = rg * 16 + (t >> 4);
    const int col = (t & 15) * 4;
    const int a = A0 + row;
    const float fa = area[a];

    unsigned sx = 0, sy = 0, sz = 0, sw = 0;
    #pragma unroll
    for (int kq = 0; kq < KQ; ++kq) {
        const uint4 v = *(const uint4*)(partial + ((size_t)kq * NPAIRS + p) * (128 * 64) + row * 64 + col);
        sx += v.x; sy += v.y; sz += v.z; sw += v.w;
    }
    const unsigned sums[4] = { sx, sy, sz, sw };

    float mLA = 0.0f;
    #pragma unroll
    for (int j = 0; j < 4; ++j) {
        const int b = B0 + col + j;
        if (a > b) continue;
        const float inter = (float)sums[j];
        const float fb = aB[col + j];
        const float uni = (fb + fa) - inter;
        const float iou = inter / (uni + 1e-8f);
        const float ra = inter / (fa + 1e-8f);   // ratio_i (row a)
        const float rb = inter / (fb + 1e-8f);   // ratio_j (col b)
        const float v = __fsub_rn(1.0f, __fmul_rn(rb, ra));
        const float iab = (ra < 0.5f && rb >= 0.85f) ? v : 0.0f;
        const float iba = (rb < 0.5f && ra >= 0.85f) ? v : 0.0f;
        if (a < b) {
            atomicMax(&redI[col + j], __float_as_uint(iou));
            atomicMax(&redU[col + j], __float_as_uint(iab));   // inner[a,b] -> innu[b]
            mLA = fmaxf(mLA, iba);                             // inner[b,a] -> innl[a]
        }
        if (a == b - 1) atomicMax(&redLB[col + j], __float_as_uint(iab)); // superdiag -> innl[b]
    }
    atomicMax(&redLA[t >> 4], __float_as_uint(mLA));
    __syncthreads();
    if (t < 64) {
        atomicMax(&ioumax[B0 + t], redI[t]);
        atomicMax(&innu[B0 + t], redU[t]);
        atomicMax(&innl[B0 + t], redLB[t]);
    }
    if (t < 16) atomicMax(&innl[A0 + rg * 16 + t], redLA[t]);
}

// ---------------- Kernel E: final keep ----------------
__global__ __launch_bounds__(256) void keep_kernel(const float* __restrict__ ssort,
                                                   const unsigned* __restrict__ ioumax,
                                                   const unsigned* __restrict__ innu,
                                                   const unsigned* __restrict__ innl,
                                                   int* __restrict__ out_keep) {
    const int r = blockIdx.x * 256 + threadIdx.x;
    const float s0 = ssort[0];
    const bool conf = (s0 > 0.7f) ? (ssort[r] > 0.7f) : (r < 3);
    const bool keep = (__uint_as_float(ioumax[r]) <= 0.8f) && conf &&
                      (__uint_as_float(innu[r]) <= 0.5f) &&
                      (__uint_as_float(innl[r]) <= 0.5f);
    out_keep[r] = keep ? 1 : 0;
}

extern "C" void kernel_launch(void* const* d_in, const int* in_sizes, int n_in,
                              void* d_out, int out_size, void* d_ws, size_t ws_size,
                              hipStream_t stream) {
    const float* masks  = (const float*)d_in[0];
    const float* scores = (const float*)d_in[1];
    int* out = (int*)d_out;

    unsigned* packed  = (unsigned*)d_ws;                        // 8 MB
    unsigned* partial = packed + (size_t)N_MASKS * WPR;         // 16*72*8192 u32 = 37.75 MB
    unsigned* tail    = partial + (size_t)KQ * NPAIRS * (128 * 64);
    int*      order   = (int*)tail;
    float*    ssort   = (float*)(order + N_MASKS);
    float*    area    = (float*)(ssort + N_MASKS);
    unsigned* ioumax  = (unsigned*)(area + N_MASKS);
    unsigned* innu    = ioumax + N_MASKS;
    unsigned* innl    = innu + N_MASKS;

    sort_kernel<<<8, 128, 0, stream>>>(scores, order, ssort, out, area, ioumax, innu, innl);
    pack_kernel<<<2048, 256, 0, stream>>>(masks, order, packed, area);
    pair_kernel<<<dim3(NPAIRS, KQ), 256, 0, stream>>>(packed, partial);
    combine_kernel<<<dim3(NPAIRS, 8), 256, 0, stream>>>(partial, area, ioumax, innu, innl);
    keep_kernel<<<4, 256, 0, stream>>>(ssort, ioumax, innu, innl, out + N_MASKS);
}

// Round 7
// 500.217 us; speedup vs baseline: 1.2124x; 1.0867x over previous
//
#include <hip/hip_runtime.h>

// SamClip: N=1024 binary masks (256x256 fp32), scores[1024].
// out int32: [0:1024] = order (argsort desc, stable), [1024:2048] = keep (0/1).
//
// R7: back to multi-kernel (R6 cooperative launch failed silently).
// pair: 64x64 tiles, 4x4 acc, ROLLED g-loop (I-cache-resident body; R4 vs R5
// showed pair time is structure-dominated, not compute-dominated).
// pack: 16-deep load batches for memory-level parallelism. Full K (fixes
// R5's silent half-K bug).

#define N_MASKS 1024
#define HW 65536
#define WPR 2048          // u32 words per packed row
#define NT 16             // 16x16 grid of 64-row tiles
#define NPAIRS 136        // NT*(NT+1)/2 triangular tile pairs
#define KQ 8              // k-split: each pair block does 4 chunks of 64 words

__device__ __forceinline__ void tile_from_pair(int p, int& I, int& J) {
    int rem = p, i = 0;
    while (rem >= NT - i) { rem -= NT - i; ++i; }
    I = i; J = i + rem;
}

// ---------------- Kernel A: stable descending argsort + init ----------------
__global__ __launch_bounds__(128) void sort_kernel(const float* __restrict__ scores,
                                                   int* __restrict__ order,
                                                   float* __restrict__ ssort,
                                                   int* __restrict__ out_order,
                                                   unsigned* __restrict__ ioumax,
                                                   unsigned* __restrict__ innu,
                                                   unsigned* __restrict__ innl) {
    __shared__ float s[N_MASKS];
    const int t = threadIdx.x;
    for (int k = t; k < N_MASKS; k += 128) s[k] = scores[k];
    __syncthreads();
    const int i = blockIdx.x * 128 + t;
    const float si = s[i];
    int rank = 0;
    #pragma unroll 8
    for (int j = 0; j < N_MASKS; ++j) {
        const float sj = s[j];
        rank += (int)((sj > si) || (sj == si && j < i));
    }
    order[rank] = i;
    ssort[rank] = si;
    out_order[rank] = i;
    ioumax[i] = 0u; innu[i] = 0u; innl[i] = 0u;
}

// ---------------- Kernel B: bitpack (sorted order) + area ----------------
// 2 blocks per mask (half each). 2 iterations x 16 float4 loads in flight.
__global__ __launch_bounds__(256, 4) void pack_kernel(const float* __restrict__ masks,
                                                      const int* __restrict__ order,
                                                      unsigned* __restrict__ packed,
                                                      float* __restrict__ area) {
    const int b = blockIdx.x;
    const int r = b >> 1, half = b & 1;
    const int src = order[r];
    const float4* __restrict__ row = (const float4*)(masks + (size_t)src * HW) + half * 8192;
    unsigned* __restrict__ prow = packed + (size_t)r * WPR + half * 1024;
    const int t = threadIdx.x;
    int cnt = 0;
    #pragma unroll
    for (int h = 0; h < 2; ++h) {
        float4 f[16];
        #pragma unroll
        for (int k = 0; k < 16; ++k)
            f[k] = row[h * 4096 + k * 256 + t];       // 16 independent loads in flight
        unsigned w0 = 0u, w1 = 0u;
        #pragma unroll
        for (int k = 0; k < 8; ++k) {
            unsigned nib = (unsigned)(f[k].x != 0.0f) | ((unsigned)(f[k].y != 0.0f) << 1)
                         | ((unsigned)(f[k].z != 0.0f) << 2) | ((unsigned)(f[k].w != 0.0f) << 3);
            w0 |= nib << (k * 4);
            unsigned nib2 = (unsigned)(f[k + 8].x != 0.0f) | ((unsigned)(f[k + 8].y != 0.0f) << 1)
                          | ((unsigned)(f[k + 8].z != 0.0f) << 2) | ((unsigned)(f[k + 8].w != 0.0f) << 3);
            w1 |= nib2 << (k * 4);
        }
        prow[h * 512 + t] = w0;
        prow[h * 512 + 256 + t] = w1;
        cnt += __builtin_popcount(w0) + __builtin_popcount(w1);
    }
    for (int off = 32; off > 0; off >>= 1) cnt += __shfl_down(cnt, off, 64);
    __shared__ int red[4];
    const int lane = t & 63, w = t >> 6;
    if (lane == 0) red[w] = cnt;
    __syncthreads();
    if (t == 0) atomicAdd(area + r, (float)(red[0] + red[1] + red[2] + red[3]));
}

// ---------------- Kernel C: pairwise popcount partials ----------------
// Block (p, kq): 64x64 tile pair p (I<=J), 4 chunks of 64 words (full K
// across KQ=8). LDS swizzle: logical (row, 16B-chunk c16) at physical chunk
// c16 ^ (row>>2): b-reads 16 distinct chunks across tx (free), a-reads
// 4-address broadcast. g-loop kept ROLLED (unroll 4) for I-cache residency.
__global__ __launch_bounds__(256, 4) void pair_kernel(const unsigned* __restrict__ packed,
                                                      unsigned* __restrict__ partial) {
    __shared__ __align__(16) unsigned lA[64 * 64];    // 16 KB
    __shared__ __align__(16) unsigned lB[64 * 64];    // 16 KB

    const int p = blockIdx.x, kq = blockIdx.y;
    int I, J; tile_from_pair(p, I, J);
    const int A0 = I * 64, B0 = J * 64;
    const int t = threadIdx.x;
    const int tx = t & 15, ty = t >> 4;

    unsigned acc[4][4] = {};

    #pragma unroll 1
    for (int cc = 0; cc < 4; ++cc) {
        const int ch = kq * 4 + cc;                   // 64-word chunk index [0,32)
        __syncthreads();
        #pragma unroll
        for (int it = 0; it < 4; ++it) {
            const int linear = it * 256 + t;          // [0,1024) uint4 slots
            const int row = linear >> 4, c16 = linear & 15;
            const int phys = row * 64 + (((c16 ^ (row >> 2)) & 15) << 2);
            const uint4 va = *(const uint4*)(packed + (size_t)(A0 + row) * WPR + ch * 64 + c16 * 4);
            const uint4 vb = *(const uint4*)(packed + (size_t)(B0 + row) * WPR + ch * 64 + c16 * 4);
            *(uint4*)(lA + phys) = va;
            *(uint4*)(lB + phys) = vb;
        }
        __syncthreads();
        #pragma unroll 4
        for (int g = 0; g < 16; ++g) {
            uint4 a[4], b[4];
            #pragma unroll
            for (int i = 0; i < 4; ++i)
                a[i] = *(const uint4*)(lA + (ty * 4 + i) * 64 + (((g ^ ty) & 15) << 2));
            #pragma unroll
            for (int j = 0; j < 4; ++j)
                b[j] = *(const uint4*)(lB + (tx * 4 + j) * 64 + (((g ^ tx) & 15) << 2));
            #pragma unroll
            for (int i = 0; i < 4; ++i)
                #pragma unroll
                for (int j = 0; j < 4; ++j) {
                    unsigned s = acc[i][j];
                    s = s + __builtin_popcount(a[i].x & b[j].x);
                    s = s + __builtin_popcount(a[i].y & b[j].y);
                    s = s + __builtin_popcount(a[i].z & b[j].z);
                    s = s + __builtin_popcount(a[i].w & b[j].w);
                    acc[i][j] = s;
                }
        }
    }

    unsigned* __restrict__ out = partial + ((size_t)kq * NPAIRS + p) * 4096;
    #pragma unroll
    for (int i = 0; i < 4; ++i)
        *(uint4*)(out + (ty * 4 + i) * 64 + tx * 4) =
            make_uint4(acc[i][0], acc[i][1], acc[i][2], acc[i][3]);
}

// ---------------- Kernel D: combine partials + epilogue + column max ----------------
// Grid (NPAIRS, 4): block handles 16 rows x 64 cols of 64x64 tile p.
__global__ __launch_bounds__(256) void combine_kernel(const unsigned* __restrict__ partial,
                                                      const float* __restrict__ area,
                                                      unsigned* __restrict__ ioumax,
                                                      unsigned* __restrict__ innu,
                                                      unsigned* __restrict__ innl) {
    __shared__ unsigned redI[64], redU[64], redLB[64], redLA[16];
    __shared__ float aB[64];

    const int p = blockIdx.x, rg = blockIdx.y;
    int I, J; tile_from_pair(p, I, J);
    const int A0 = I * 64, B0 = J * 64;
    const int t = threadIdx.x;
    if (t < 64) { redI[t] = 0u; redU[t] = 0u; redLB[t] = 0u; aB[t] = area[B0 + t]; }
    if (t < 16) redLA[t] = 0u;
    __syncthreads();

    const int row = rg * 16 + (t >> 4);               // [0,64)
    const int col = (t & 15) * 4;
    const int a = A0 + row;
    const float fa = area[a];

    unsigned sx = 0, sy = 0, sz = 0, sw = 0;
    #pragma unroll
    for (int kq = 0; kq < KQ; ++kq) {
        const uint4 v = *(const uint4*)(partial + ((size_t)kq * NPAIRS + p) * 4096 + row * 64 + col);
        sx += v.x; sy += v.y; sz += v.z; sw += v.w;
    }
    const unsigned sums[4] = { sx, sy, sz, sw };

    float mLA = 0.0f;
    #pragma unroll
    for (int j = 0; j < 4; ++j) {
        const int b = B0 + col + j;
        if (a > b) continue;
        const float inter = (float)sums[j];
        const float fb = aB[col + j];
        const float uni = (fb + fa) - inter;
        const float iou = inter / (uni + 1e-8f);
        const float ra = inter / (fa + 1e-8f);        // ratio_i (row a)
        const float rb = inter / (fb + 1e-8f);        // ratio_j (col b)
        const float v = __fsub_rn(1.0f, __fmul_rn(rb, ra));
        const float iab = (ra < 0.5f && rb >= 0.85f) ? v : 0.0f;
        const float iba = (rb < 0.5f && ra >= 0.85f) ? v : 0.0f;
        if (a < b) {
            atomicMax(&redI[col + j], __float_as_uint(iou));
            atomicMax(&redU[col + j], __float_as_uint(iab));   // inner[a,b] -> innu[b]
            mLA = fmaxf(mLA, iba);                             // inner[b,a] -> innl[a]
        }
        if (a == b - 1) atomicMax(&redLB[col + j], __float_as_uint(iab)); // superdiag -> innl[b]
    }
    atomicMax(&redLA[t >> 4], __float_as_uint(mLA));
    __syncthreads();
    if (t < 64) {
        atomicMax(&ioumax[B0 + t], redI[t]);
        atomicMax(&innu[B0 + t], redU[t]);
        atomicMax(&innl[B0 + t], redLB[t]);
    }
    if (t < 16) atomicMax(&innl[A0 + rg * 16 + t], redLA[t]);
}

// ---------------- Kernel E: final keep ----------------
__global__ __launch_bounds__(256) void keep_kernel(const float* __restrict__ ssort,
                                                   const unsigned* __restrict__ ioumax,
                                                   const unsigned* __restrict__ innu,
                                                   const unsigned* __restrict__ innl,
                                                   int* __restrict__ out_keep) {
    const int r = blockIdx.x * 256 + threadIdx.x;
    const float s0 = ssort[0];
    const bool conf = (s0 > 0.7f) ? (ssort[r] > 0.7f) : (r < 3);
    const bool keep = (__uint_as_float(ioumax[r]) <= 0.8f) && conf &&
                      (__uint_as_float(innu[r]) <= 0.5f) &&
                      (__uint_as_float(innl[r]) <= 0.5f);
    out_keep[r] = keep ? 1 : 0;
}

extern "C" void kernel_launch(void* const* d_in, const int* in_sizes, int n_in,
                              void* d_out, int out_size, void* d_ws, size_t ws_size,
                              hipStream_t stream) {
    const float* masks  = (const float*)d_in[0];
    const float* scores = (const float*)d_in[1];
    int* out = (int*)d_out;

    unsigned* packed  = (unsigned*)d_ws;                        // 8 MB
    unsigned* partial = packed + (size_t)N_MASKS * WPR;         // 8*136*4096 u32 = 17.8 MB
    unsigned* tail    = partial + (size_t)KQ * NPAIRS * 4096;
    int*      order   = (int*)tail;
    float*    ssort   = (float*)(order + N_MASKS);
    float*    area    = (float*)(ssort + N_MASKS);
    unsigned* ioumax  = (unsigned*)(area + N_MASKS);
    unsigned* innu    = ioumax + N_MASKS;
    unsigned* innl    = innu + N_MASKS;

    // area zero-init must happen before pack's atomicAdd
    hipMemsetAsync(area, 0, N_MASKS * sizeof(float), stream);
    sort_kernel<<<8, 128, 0, stream>>>(scores, order, ssort, out, ioumax, innu, innl);
    pack_kernel<<<2048, 256, 0, stream>>>(masks, order, packed, area);
    pair_kernel<<<dim3(NPAIRS, KQ), 256, 0, stream>>>(packed, partial);
    combine_kernel<<<dim3(NPAIRS, 4), 256, 0, stream>>>(partial, area, ioumax, innu, innl);
    keep_kernel<<<4, 256, 0, stream>>>(ssort, ioumax, innu, innl, out + N_MASKS);
}

// Round 8
// 472.689 us; speedup vs baseline: 1.2830x; 1.0582x over previous
//
#include <hip/hip_runtime.h>

// SamClip: N=1024 binary masks (256x256 fp32), scores[1024].
// out int32: [0:1024] = order (argsort desc, stable), [1024:2048] = keep (0/1).
//
// R8: R7 structure (best so far) with pack pushed to its BW floor:
// 4096 blocks (16/CU), one batch of 16 nontemporal float4 loads per thread
// (max MLP, no L2/L3 pollution of the packed buffer), area-memset folded
// into sort_kernel. pair/combine unchanged from R7 (rolled g-loop).

#define N_MASKS 1024
#define HW 65536
#define WPR 2048          // u32 words per packed row
#define NT 16             // 16x16 grid of 64-row tiles
#define NPAIRS 136        // NT*(NT+1)/2 triangular tile pairs
#define KQ 8              // k-split: each pair block does 4 chunks of 64 words

typedef float vfloat4 __attribute__((ext_vector_type(4)));

__device__ __forceinline__ void tile_from_pair(int p, int& I, int& J) {
    int rem = p, i = 0;
    while (rem >= NT - i) { rem -= NT - i; ++i; }
    I = i; J = i + rem;
}

// ---------------- Kernel A: stable descending argsort + init ----------------
__global__ __launch_bounds__(128) void sort_kernel(const float* __restrict__ scores,
                                                   int* __restrict__ order,
                                                   float* __restrict__ ssort,
                                                   int* __restrict__ out_order,
                                                   float* __restrict__ area,
                                                   unsigned* __restrict__ ioumax,
                                                   unsigned* __restrict__ innu,
                                                   unsigned* __restrict__ innl) {
    __shared__ float s[N_MASKS];
    const int t = threadIdx.x;
    for (int k = t; k < N_MASKS; k += 128) s[k] = scores[k];
    __syncthreads();
    const int i = blockIdx.x * 128 + t;
    const float si = s[i];
    int rank = 0;
    #pragma unroll 8
    for (int j = 0; j < N_MASKS; ++j) {
        const float sj = s[j];
        rank += (int)((sj > si) || (sj == si && j < i));
    }
    order[rank] = i;
    ssort[rank] = si;
    out_order[rank] = i;
    area[i] = 0.0f;                 // zero-init for pack's atomicAdd
    ioumax[i] = 0u; innu[i] = 0u; innl[i] = 0u;
}

// ---------------- Kernel B: bitpack (sorted order) + area ----------------
// 4 blocks per mask (quarter-row each). One batch of 16 nontemporal float4
// loads in flight per thread; each thread emits 2 packed words.
__global__ __launch_bounds__(256, 4) void pack_kernel(const float* __restrict__ masks,
                                                      const int* __restrict__ order,
                                                      unsigned* __restrict__ packed,
                                                      float* __restrict__ area) {
    const int b = blockIdx.x;
    const int r = b >> 2, q = b & 3;
    const int src = order[r];
    const vfloat4* __restrict__ row = (const vfloat4*)(masks + (size_t)src * HW) + q * 4096;
    unsigned* __restrict__ prow = packed + (size_t)r * WPR + q * 512;
    const int t = threadIdx.x;

    vfloat4 f[16];
    #pragma unroll
    for (int k = 0; k < 16; ++k)
        f[k] = __builtin_nontemporal_load(row + k * 256 + t);   // 16 loads in flight

    unsigned w0 = 0u, w1 = 0u;
    #pragma unroll
    for (int k = 0; k < 8; ++k) {
        const unsigned nib0 = (unsigned)(f[k][0] != 0.0f)       | ((unsigned)(f[k][1] != 0.0f) << 1)
                            | ((unsigned)(f[k][2] != 0.0f) << 2) | ((unsigned)(f[k][3] != 0.0f) << 3);
        w0 |= nib0 << (k * 4);
        const unsigned nib1 = (unsigned)(f[k + 8][0] != 0.0f)       | ((unsigned)(f[k + 8][1] != 0.0f) << 1)
                            | ((unsigned)(f[k + 8][2] != 0.0f) << 2) | ((unsigned)(f[k + 8][3] != 0.0f) << 3);
        w1 |= nib1 << (k * 4);
    }
    prow[t] = w0;
    prow[256 + t] = w1;

    int cnt = __builtin_popcount(w0) + __builtin_popcount(w1);
    for (int off = 32; off > 0; off >>= 1) cnt += __shfl_down(cnt, off, 64);
    __shared__ int red[4];
    const int lane = t & 63, w = t >> 6;
    if (lane == 0) red[w] = cnt;
    __syncthreads();
    if (t == 0) atomicAdd(area + r, (float)(red[0] + red[1] + red[2] + red[3]));
}

// ---------------- Kernel C: pairwise popcount partials ----------------
// Block (p, kq): 64x64 tile pair p (I<=J), 4 chunks of 64 words. LDS swizzle:
// logical (row, 16B-chunk c16) at physical chunk c16 ^ (row>>2): b-reads hit
// 16 distinct chunks across tx (free), a-reads 4-address broadcast. g-loop
// ROLLED (unroll 4) for I-cache residency.
__global__ __launch_bounds__(256, 4) void pair_kernel(const unsigned* __restrict__ packed,
                                                      unsigned* __restrict__ partial) {
    __shared__ __align__(16) unsigned lA[64 * 64];    // 16 KB
    __shared__ __align__(16) unsigned lB[64 * 64];    // 16 KB

    const int p = blockIdx.x, kq = blockIdx.y;
    int I, J; tile_from_pair(p, I, J);
    const int A0 = I * 64, B0 = J * 64;
    const int t = threadIdx.x;
    const int tx = t & 15, ty = t >> 4;

    unsigned acc[4][4] = {};

    #pragma unroll 1
    for (int cc = 0; cc < 4; ++cc) {
        const int ch = kq * 4 + cc;                   // 64-word chunk index [0,32)
        __syncthreads();
        #pragma unroll
        for (int it = 0; it < 4; ++it) {
            const int linear = it * 256 + t;          // [0,1024) uint4 slots
            const int row = linear >> 4, c16 = linear & 15;
            const int phys = row * 64 + (((c16 ^ (row >> 2)) & 15) << 2);
            const uint4 va = *(const uint4*)(packed + (size_t)(A0 + row) * WPR + ch * 64 + c16 * 4);
            const uint4 vb = *(const uint4*)(packed + (size_t)(B0 + row) * WPR + ch * 64 + c16 * 4);
            *(uint4*)(lA + phys) = va;
            *(uint4*)(lB + phys) = vb;
        }
        __syncthreads();
        #pragma unroll 4
        for (int g = 0; g < 16; ++g) {
            uint4 a[4], b[4];
            #pragma unroll
            for (int i = 0; i < 4; ++i)
                a[i] = *(const uint4*)(lA + (ty * 4 + i) * 64 + (((g ^ ty) & 15) << 2));
            #pragma unroll
            for (int j = 0; j < 4; ++j)
                b[j] = *(const uint4*)(lB + (tx * 4 + j) * 64 + (((g ^ tx) & 15) << 2));
            #pragma unroll
            for (int i = 0; i < 4; ++i)
                #pragma unroll
                for (int j = 0; j < 4; ++j) {
                    unsigned s = acc[i][j];
                    s = s + __builtin_popcount(a[i].x & b[j].x);
                    s = s + __builtin_popcount(a[i].y & b[j].y);
                    s = s + __builtin_popcount(a[i].z & b[j].z);
                    s = s + __builtin_popcount(a[i].w & b[j].w);
                    acc[i][j] = s;
                }
        }
    }

    unsigned* __restrict__ out = partial + ((size_t)kq * NPAIRS + p) * 4096;
    #pragma unroll
    for (int i = 0; i < 4; ++i)
        *(uint4*)(out + (ty * 4 + i) * 64 + tx * 4) =
            make_uint4(acc[i][0], acc[i][1], acc[i][2], acc[i][3]);
}

// ---------------- Kernel D: combine partials + epilogue + column max ----------------
// Grid (NPAIRS, 4): block handles 16 rows x 64 cols of 64x64 tile p.
__global__ __launch_bounds__(256) void combine_kernel(const unsigned* __restrict__ partial,
                                                      const float* __restrict__ area,
                                                      unsigned* __restrict__ ioumax,
                                                      unsigned* __restrict__ innu,
                                                      unsigned* __restrict__ innl) {
    __shared__ unsigned redI[64], redU[64], redLB[64], redLA[16];
    __shared__ float aB[64];

    const int p = blockIdx.x, rg = blockIdx.y;
    int I, J; tile_from_pair(p, I, J);
    const int A0 = I * 64, B0 = J * 64;
    const int t = threadIdx.x;
    if (t < 64) { redI[t] = 0u; redU[t] = 0u; redLB[t] = 0u; aB[t] = area[B0 + t]; }
    if (t < 16) redLA[t] = 0u;
    __syncthreads();

    const int row = rg * 16 + (t >> 4);               // [0,64)
    const int col = (t & 15) * 4;
    const int a = A0 + row;
    const float fa = area[a];

    unsigned sx = 0, sy = 0, sz = 0, sw = 0;
    #pragma unroll
    for (int kq = 0; kq < KQ; ++kq) {
        const uint4 v = *(const uint4*)(partial + ((size_t)kq * NPAIRS + p) * 4096 + row * 64 + col);
        sx += v.x; sy += v.y; sz += v.z; sw += v.w;
    }
    const unsigned sums[4] = { sx, sy, sz, sw };

    float mLA = 0.0f;
    #pragma unroll
    for (int j = 0; j < 4; ++j) {
        const int b = B0 + col + j;
        if (a > b) continue;
        const float inter = (float)sums[j];
        const float fb = aB[col + j];
        const float uni = (fb + fa) - inter;
        const float iou = inter / (uni + 1e-8f);
        const float ra = inter / (fa + 1e-8f);        // ratio_i (row a)
        const float rb = inter / (fb + 1e-8f);        // ratio_j (col b)
        const float v = __fsub_rn(1.0f, __fmul_rn(rb, ra));
        const float iab = (ra < 0.5f && rb >= 0.85f) ? v : 0.0f;
        const float iba = (rb < 0.5f && ra >= 0.85f) ? v : 0.0f;
        if (a < b) {
            atomicMax(&redI[col + j], __float_as_uint(iou));
            atomicMax(&redU[col + j], __float_as_uint(iab));   // inner[a,b] -> innu[b]
            mLA = fmaxf(mLA, iba);                             // inner[b,a] -> innl[a]
        }
        if (a == b - 1) atomicMax(&redLB[col + j], __float_as_uint(iab)); // superdiag -> innl[b]
    }
    atomicMax(&redLA[t >> 4], __float_as_uint(mLA));
    __syncthreads();
    if (t < 64) {
        atomicMax(&ioumax[B0 + t], redI[t]);
        atomicMax(&innu[B0 + t], redU[t]);
        atomicMax(&innl[B0 + t], redLB[t]);
    }
    if (t < 16) atomicMax(&innl[A0 + rg * 16 + t], redLA[t]);
}

// ---------------- Kernel E: final keep ----------------
__global__ __launch_bounds__(256) void keep_kernel(const float* __restrict__ ssort,
                                                   const unsigned* __restrict__ ioumax,
                                                   const unsigned* __restrict__ innu,
                                                   const unsigned* __restrict__ innl,
                                                   int* __restrict__ out_keep) {
    const int r = blockIdx.x * 256 + threadIdx.x;
    const float s0 = ssort[0];
    const bool conf = (s0 > 0.7f) ? (ssort[r] > 0.7f) : (r < 3);
    const bool keep = (__uint_as_float(ioumax[r]) <= 0.8f) && conf &&
                      (__uint_as_float(innu[r]) <= 0.5f) &&
                      (__uint_as_float(innl[r]) <= 0.5f);
    out_keep[r] = keep ? 1 : 0;
}

extern "C" void kernel_launch(void* const* d_in, const int* in_sizes, int n_in,
                              void* d_out, int out_size, void* d_ws, size_t ws_size,
                              hipStream_t stream) {
    const float* masks  = (const float*)d_in[0];
    const float* scores = (const float*)d_in[1];
    int* out = (int*)d_out;

    unsigned* packed  = (unsigned*)d_ws;                        // 8 MB
    unsigned* partial = packed + (size_t)N_MASKS * WPR;         // 8*136*4096 u32 = 17.8 MB
    unsigned* tail    = partial + (size_t)KQ * NPAIRS * 4096;
    int*      order   = (int*)tail;
    float*    ssort   = (float*)(order + N_MASKS);
    float*    area    = (float*)(ssort + N_MASKS);
    unsigned* ioumax  = (unsigned*)(area + N_MASKS);
    unsigned* innu    = ioumax + N_MASKS;
    unsigned* innl    = innu + N_MASKS;

    sort_kernel<<<8, 128, 0, stream>>>(scores, order, ssort, out, area, ioumax, innu, innl);
    pack_kernel<<<4096, 256, 0, stream>>>(masks, order, packed, area);
    pair_kernel<<<dim3(NPAIRS, KQ), 256, 0, stream>>>(packed, partial);
    combine_kernel<<<dim3(NPAIRS, 4), 256, 0, stream>>>(partial, area, ioumax, innu, innl);
    keep_kernel<<<4, 256, 0, stream>>>(ssort, ioumax, innu, innl, out + N_MASKS);
}

// Round 9
// 437.536 us; speedup vs baseline: 1.3861x; 1.0803x over previous
//
#include <hip/hip_runtime.h>

// SamClip: N=1024 binary masks (256x256 fp32), scores[1024].
// out int32: [0:1024] = order (argsort desc, stable), [1024:2048] = keep (0/1).
//
// R9: pair kernel moved to the MATRIX pipe: inter = i8 GEMM via
// v_mfma_i32_32x32x32_i8 (4404 TOPS, i32-exact). Masks stay bitpacked in
// HBM (8 MB, L2-resident); bit->byte expansion happens during LDS staging
// (nibble * 0x204081 & 0x01010101). 128x128 triangular tiles, KQ=16 k-split,
// 2x2 32-wide MFMA tiles per wave. pack/sort/keep/combine from R8/R3.

#define N_MASKS 1024
#define HW 65536
#define WPR 2048          // u32 words per packed row
#define NT 8              // 8x8 grid of 128-row tiles
#define NPAIRS 36         // NT*(NT+1)/2
#define KQ 16             // k-split: each pair block covers 128 words (4096 bytes)

typedef float vfloat4 __attribute__((ext_vector_type(4)));
typedef int v4i __attribute__((ext_vector_type(4)));
typedef int v16i __attribute__((ext_vector_type(16)));

__device__ __forceinline__ void tile_from_pair(int p, int& I, int& J) {
    int rem = p, i = 0;
    while (rem >= NT - i) { rem -= NT - i; ++i; }
    I = i; J = i + rem;
}

// ---------------- Kernel A: stable descending argsort + init ----------------
__global__ __launch_bounds__(128) void sort_kernel(const float* __restrict__ scores,
                                                   int* __restrict__ order,
                                                   float* __restrict__ ssort,
                                                   int* __restrict__ out_order,
                                                   float* __restrict__ area,
                                                   unsigned* __restrict__ ioumax,
                                                   unsigned* __restrict__ innu,
                                                   unsigned* __restrict__ innl) {
    __shared__ float s[N_MASKS];
    const int t = threadIdx.x;
    for (int k = t; k < N_MASKS; k += 128) s[k] = scores[k];
    __syncthreads();
    const int i = blockIdx.x * 128 + t;
    const float si = s[i];
    int rank = 0;
    #pragma unroll 8
    for (int j = 0; j < N_MASKS; ++j) {
        const float sj = s[j];
        rank += (int)((sj > si) || (sj == si && j < i));
    }
    order[rank] = i;
    ssort[rank] = si;
    out_order[rank] = i;
    area[i] = 0.0f;
    ioumax[i] = 0u; innu[i] = 0u; innl[i] = 0u;
}

// ---------------- Kernel B: bitpack (sorted order) + area (R8 form) ----------------
__global__ __launch_bounds__(256, 4) void pack_kernel(const float* __restrict__ masks,
                                                      const int* __restrict__ order,
                                                      unsigned* __restrict__ packed,
                                                      float* __restrict__ area) {
    const int b = blockIdx.x;
    const int r = b >> 2, q = b & 3;
    const int src = order[r];
    const vfloat4* __restrict__ row = (const vfloat4*)(masks + (size_t)src * HW) + q * 4096;
    unsigned* __restrict__ prow = packed + (size_t)r * WPR + q * 512;
    const int t = threadIdx.x;

    vfloat4 f[16];
    #pragma unroll
    for (int k = 0; k < 16; ++k)
        f[k] = __builtin_nontemporal_load(row + k * 256 + t);

    unsigned w0 = 0u, w1 = 0u;
    #pragma unroll
    for (int k = 0; k < 8; ++k) {
        const unsigned nib0 = (unsigned)(f[k][0] != 0.0f)        | ((unsigned)(f[k][1] != 0.0f) << 1)
                            | ((unsigned)(f[k][2] != 0.0f) << 2) | ((unsigned)(f[k][3] != 0.0f) << 3);
        w0 |= nib0 << (k * 4);
        const unsigned nib1 = (unsigned)(f[k + 8][0] != 0.0f)        | ((unsigned)(f[k + 8][1] != 0.0f) << 1)
                            | ((unsigned)(f[k + 8][2] != 0.0f) << 2) | ((unsigned)(f[k + 8][3] != 0.0f) << 3);
        w1 |= nib1 << (k * 4);
    }
    prow[t] = w0;
    prow[256 + t] = w1;

    int cnt = __builtin_popcount(w0) + __builtin_popcount(w1);
    for (int off = 32; off > 0; off >>= 1) cnt += __shfl_down(cnt, off, 64);
    __shared__ int red[4];
    const int lane = t & 63, w = t >> 6;
    if (lane == 0) red[w] = cnt;
    __syncthreads();
    if (t == 0) atomicAdd(area + r, (float)(red[0] + red[1] + red[2] + red[3]));
}

// ---------------- Kernel C: pairwise inter via i8 MFMA ----------------
// Block (p, kq): 128x128 tile pair p (I<=J), k-range = 128 words = 4096 bytes.
// 16 chunks of 8 words (256 bytes). Staging expands bits->0/1 bytes into LDS
// (rows of 256 B = 16 chunks of 16 B, phys chunk = c ^ (row&15) swizzle).
// 4 waves, each owns a 64x64 output quadrant = 2x2 mfma_i32_32x32x32_i8 tiles.
// A-frag: row=lane&31, k=(lane>>5)*16+[0,16). C/D: col=lane&31,
// row=(reg&3)+8*(reg>>2)+4*(lane>>5)  [guide §3, m74/m101].
__global__ __launch_bounds__(256, 2) void pair_kernel(const unsigned* __restrict__ packed,
                                                      int* __restrict__ partial) {
    __shared__ __align__(16) unsigned lA[128 * 64];   // 128 rows x 256 bytes = 32 KB
    __shared__ __align__(16) unsigned lB[128 * 64];   // 32 KB

    const int p = blockIdx.x, kq = blockIdx.y;
    int I, J; tile_from_pair(p, I, J);
    const int A0 = I * 128, B0 = J * 128;
    const int t = threadIdx.x;
    const int wave = t >> 6, lane = t & 63, half = lane >> 5, lr = lane & 31;
    const int wr = (wave >> 1) * 64, wc = (wave & 1) * 64;
    const int srow = t & 127, shalf = t >> 7;         // staging: row, word-half

    v16i acc[2][2];
    #pragma unroll
    for (int i = 0; i < 2; ++i)
        #pragma unroll
        for (int j = 0; j < 2; ++j)
            #pragma unroll
            for (int r = 0; r < 16; ++r) acc[i][j][r] = 0;

    const int sw = srow & 15;

    #pragma unroll 1
    for (int ch = 0; ch < 16; ++ch) {
        __syncthreads();
        const uint4 wa = *(const uint4*)(packed + (size_t)(A0 + srow) * WPR + kq * 128 + ch * 8 + shalf * 4);
        const uint4 wb = *(const uint4*)(packed + (size_t)(B0 + srow) * WPR + kq * 128 + ch * 8 + shalf * 4);
        #pragma unroll
        for (int w = 0; w < 4; ++w) {
            const unsigned a = (w == 0) ? wa.x : (w == 1) ? wa.y : (w == 2) ? wa.z : wa.w;
            const unsigned b = (w == 0) ? wb.x : (w == 1) ? wb.y : (w == 2) ? wb.z : wb.w;
            const int wcid = shalf * 4 + w;           // word index in row [0,8)
            uint4 lo, hi;
            lo.x = ((a         & 0xFu) * 0x00204081u) & 0x01010101u;
            lo.y = (((a >> 4)  & 0xFu) * 0x00204081u) & 0x01010101u;
            lo.z = (((a >> 8)  & 0xFu) * 0x00204081u) & 0x01010101u;
            lo.w = (((a >> 12) & 0xFu) * 0x00204081u) & 0x01010101u;
            hi.x = (((a >> 16) & 0xFu) * 0x00204081u) & 0x01010101u;
            hi.y = (((a >> 20) & 0xFu) * 0x00204081u) & 0x01010101u;
            hi.z = (((a >> 24) & 0xFu) * 0x00204081u) & 0x01010101u;
            hi.w = (((a >> 28) & 0xFu) * 0x00204081u) & 0x01010101u;
            *(uint4*)(lA + srow * 64 + (((wcid * 2)     ^ sw) << 2)) = lo;
            *(uint4*)(lA + srow * 64 + (((wcid * 2 + 1) ^ sw) << 2)) = hi;
            lo.x = ((b         & 0xFu) * 0x00204081u) & 0x01010101u;
            lo.y = (((b >> 4)  & 0xFu) * 0x00204081u) & 0x01010101u;
            lo.z = (((b >> 8)  & 0xFu) * 0x00204081u) & 0x01010101u;
            lo.w = (((b >> 12) & 0xFu) * 0x00204081u) & 0x01010101u;
            hi.x = (((b >> 16) & 0xFu) * 0x00204081u) & 0x01010101u;
            hi.y = (((b >> 20) & 0xFu) * 0x00204081u) & 0x01010101u;
            hi.z = (((b >> 24) & 0xFu) * 0x00204081u) & 0x01010101u;
            hi.w = (((b >> 28) & 0xFu) * 0x00204081u) & 0x01010101u;
            *(uint4*)(lB + srow * 64 + (((wcid * 2)     ^ sw) << 2)) = lo;
            *(uint4*)(lB + srow * 64 + (((wcid * 2 + 1) ^ sw) << 2)) = hi;
        }
        __syncthreads();

        #pragma unroll
        for (int kk = 0; kk < 8; ++kk) {              // k-step = 32 bytes = 1 word
            const int phys = ((kk * 2 + half) ^ (lr & 15)) << 2;
            const v4i a0 = *(const v4i*)(lA + (wr + lr) * 64 + phys);
            const v4i a1 = *(const v4i*)(lA + (wr + 32 + lr) * 64 + phys);
            const v4i b0 = *(const v4i*)(lB + (wc + lr) * 64 + phys);
            const v4i b1 = *(const v4i*)(lB + (wc + 32 + lr) * 64 + phys);
            acc[0][0] = __builtin_amdgcn_mfma_i32_32x32x32_i8(a0, b0, acc[0][0], 0, 0, 0);
            acc[0][1] = __builtin_amdgcn_mfma_i32_32x32x32_i8(a0, b1, acc[0][1], 0, 0, 0);
            acc[1][0] = __builtin_amdgcn_mfma_i32_32x32x32_i8(a1, b0, acc[1][0], 0, 0, 0);
            acc[1][1] = __builtin_amdgcn_mfma_i32_32x32x32_i8(a1, b1, acc[1][1], 0, 0, 0);
        }
    }

    // epilogue: partial tile 128x128 (row-major)
    int* __restrict__ outp = partial + ((size_t)kq * NPAIRS + p) * 16384;
    #pragma unroll
    for (int i = 0; i < 2; ++i)
        #pragma unroll
        for (int j = 0; j < 2; ++j)
            #pragma unroll
            for (int reg = 0; reg < 16; ++reg) {
                const int m = wr + i * 32 + (reg & 3) + 8 * (reg >> 2) + 4 * half;
                const int n = wc + j * 32 + lr;
                outp[m * 128 + n] = acc[i][j][reg];
            }
}

// ---------------- Kernel D: combine partials + epilogue + column max (R3 form) ----------------
__global__ __launch_bounds__(256) void combine_kernel(const unsigned* __restrict__ partial,
                                                      const float* __restrict__ area,
                                                      unsigned* __restrict__ ioumax,
                                                      unsigned* __restrict__ innu,
                                                      unsigned* __restrict__ innl) {
    __shared__ unsigned redI[128], redU[128], redLB[128], redLA[8];
    __shared__ float aB[128];

    const int p = blockIdx.x, rg = blockIdx.y;
    int I, J; tile_from_pair(p, I, J);
    const int A0 = I * 128, B0 = J * 128;
    const int t = threadIdx.x;
    if (t < 128) { redI[t] = 0u; redU[t] = 0u; redLB[t] = 0u; aB[t] = area[B0 + t]; }
    if (t < 8) redLA[t] = 0u;
    __syncthreads();

    const int row = rg * 8 + (t >> 5);
    const int col = (t & 31) * 4;
    const int a = A0 + row;
    const float fa = area[a];

    unsigned sx = 0, sy = 0, sz = 0, sw = 0;
    #pragma unroll
    for (int kq = 0; kq < KQ; ++kq) {
        const uint4 v = *(const uint4*)(partial + ((size_t)kq * NPAIRS + p) * 16384 + row * 128 + col);
        sx += v.x; sy += v.y; sz += v.z; sw += v.w;
    }
    const unsigned sums[4] = { sx, sy, sz, sw };

    float mLA = 0.0f;
    #pragma unroll
    for (int j = 0; j < 4; ++j) {
        const int b = B0 + col + j;
        if (a > b) continue;
        const float inter = (float)sums[j];
        const float fb = aB[col + j];
        const float uni = (fb + fa) - inter;
        const float iou = inter / (uni + 1e-8f);
        const float ra = inter / (fa + 1e-8f);        // ratio_i (row a)
        const float rb = inter / (fb + 1e-8f);        // ratio_j (col b)
        const float v = __fsub_rn(1.0f, __fmul_rn(rb, ra));
        const float iab = (ra < 0.5f && rb >= 0.85f) ? v : 0.0f;
        const float iba = (rb < 0.5f && ra >= 0.85f) ? v : 0.0f;
        if (a < b) {
            atomicMax(&redI[col + j], __float_as_uint(iou));
            atomicMax(&redU[col + j], __float_as_uint(iab));   // inner[a,b] -> innu[b]
            mLA = fmaxf(mLA, iba);                             // inner[b,a] -> innl[a]
        }
        if (a == b - 1) atomicMax(&redLB[col + j], __float_as_uint(iab)); // superdiag -> innl[b]
    }
    atomicMax(&redLA[t >> 5], __float_as_uint(mLA));
    __syncthreads();
    if (t < 128) {
        atomicMax(&ioumax[B0 + t], redI[t]);
        atomicMax(&innu[B0 + t], redU[t]);
        atomicMax(&innl[B0 + t], redLB[t]);
    }
    if (t < 8) atomicMax(&innl[A0 + rg * 8 + t], redLA[t]);
}

// ---------------- Kernel E: final keep ----------------
__global__ __launch_bounds__(256) void keep_kernel(const float* __restrict__ ssort,
                                                   const unsigned* __restrict__ ioumax,
                                                   const unsigned* __restrict__ innu,
                                                   const unsigned* __restrict__ innl,
                                                   int* __restrict__ out_keep) {
    const int r = blockIdx.x * 256 + threadIdx.x;
    const float s0 = ssort[0];
    const bool conf = (s0 > 0.7f) ? (ssort[r] > 0.7f) : (r < 3);
    const bool keep = (__uint_as_float(ioumax[r]) <= 0.8f) && conf &&
                      (__uint_as_float(innu[r]) <= 0.5f) &&
                      (__uint_as_float(innl[r]) <= 0.5f);
    out_keep[r] = keep ? 1 : 0;
}

extern "C" void kernel_launch(void* const* d_in, const int* in_sizes, int n_in,
                              void* d_out, int out_size, void* d_ws, size_t ws_size,
                              hipStream_t stream) {
    const float* masks  = (const float*)d_in[0];
    const float* scores = (const float*)d_in[1];
    int* out = (int*)d_out;

    unsigned* packed  = (unsigned*)d_ws;                        // 8 MB
    unsigned* partial = packed + (size_t)N_MASKS * WPR;         // 16*36*16384 u32 = 37.75 MB
    unsigned* tail    = partial + (size_t)KQ * NPAIRS * 16384;
    int*      order   = (int*)tail;
    float*    ssort   = (float*)(order + N_MASKS);
    float*    area    = (float*)(ssort + N_MASKS);
    unsigned* ioumax  = (unsigned*)(area + N_MASKS);
    unsigned* innu    = ioumax + N_MASKS;
    unsigned* innl    = innu + N_MASKS;

    sort_kernel<<<8, 128, 0, stream>>>(scores, order, ssort, out, area, ioumax, innu, innl);
    pack_kernel<<<4096, 256, 0, stream>>>(masks, order, packed, area);
    pair_kernel<<<dim3(NPAIRS, KQ), 256, 0, stream>>>(packed, (int*)partial);
    combine_kernel<<<dim3(NPAIRS, KQ), 256, 0, stream>>>(partial, area, ioumax, innu, innl);
    keep_kernel<<<4, 256, 0, stream>>>(ssort, ioumax, innu, innl, out + N_MASKS);
}

// Round 10
// 430.065 us; speedup vs baseline: 1.4101x; 1.0174x over previous
//
#include <hip/hip_runtime.h>

// SamClip: N=1024 binary masks (256x256 fp32), scores[1024].
// out int32: [0:1024] = order (argsort desc, stable), [1024:2048] = keep (0/1).
//
// R10: pair kernel is now LDS-FREE: each lane loads packed bits straight
// from L2 (uint4 = 4 k-steps of 32 bits), expands bits->0/1 bytes in
// registers (bfe + nibble*0x204081 & 0x01010101, 12 VALU/fragment), feeds
// v_mfma_i32_32x32x32_i8. No staging, no barriers, no LDS round-trip of the
// 8x-inflated data (R9 paid ~1.8 GB of LDS traffic for this). Diagonal
// tiles skip the all-lower-triangle quadrant (wave 2). sort/pack/combine/
// keep unchanged from R9.

#define N_MASKS 1024
#define HW 65536
#define WPR 2048          // u32 words per packed row
#define NT 8              // 8x8 grid of 128-row tiles
#define NPAIRS 36         // NT*(NT+1)/2
#define KQ 16             // k-split: each pair block covers 128 words (4096 bits)

typedef float vfloat4 __attribute__((ext_vector_type(4)));
typedef int v4i __attribute__((ext_vector_type(4)));
typedef int v16i __attribute__((ext_vector_type(16)));

__device__ __forceinline__ void tile_from_pair(int p, int& I, int& J) {
    int rem = p, i = 0;
    while (rem >= NT - i) { rem -= NT - i; ++i; }
    I = i; J = i + rem;
}

// expand 16 bits of `word` starting at bit `sh` into 16 0/1 bytes (v4i)
__device__ __forceinline__ v4i expand16(unsigned word, int sh) {
    v4i r;
    r[0] = (int)((((word >> (sh + 0))  & 0xFu) * 0x00204081u) & 0x01010101u);
    r[1] = (int)((((word >> (sh + 4))  & 0xFu) * 0x00204081u) & 0x01010101u);
    r[2] = (int)((((word >> (sh + 8))  & 0xFu) * 0x00204081u) & 0x01010101u);
    r[3] = (int)((((word >> (sh + 12)) & 0xFu) * 0x00204081u) & 0x01010101u);
    return r;
}

// ---------------- Kernel A: stable descending argsort + init ----------------
__global__ __launch_bounds__(128) void sort_kernel(const float* __restrict__ scores,
                                                   int* __restrict__ order,
                                                   float* __restrict__ ssort,
                                                   int* __restrict__ out_order,
                                                   float* __restrict__ area,
                                                   unsigned* __restrict__ ioumax,
                                                   unsigned* __restrict__ innu,
                                                   unsigned* __restrict__ innl) {
    __shared__ float s[N_MASKS];
    const int t = threadIdx.x;
    for (int k = t; k < N_MASKS; k += 128) s[k] = scores[k];
    __syncthreads();
    const int i = blockIdx.x * 128 + t;
    const float si = s[i];
    int rank = 0;
    #pragma unroll 8
    for (int j = 0; j < N_MASKS; ++j) {
        const float sj = s[j];
        rank += (int)((sj > si) || (sj == si && j < i));
    }
    order[rank] = i;
    ssort[rank] = si;
    out_order[rank] = i;
    area[i] = 0.0f;
    ioumax[i] = 0u; innu[i] = 0u; innl[i] = 0u;
}

// ---------------- Kernel B: bitpack (sorted order) + area (R8 form) ----------------
__global__ __launch_bounds__(256, 4) void pack_kernel(const float* __restrict__ masks,
                                                      const int* __restrict__ order,
                                                      unsigned* __restrict__ packed,
                                                      float* __restrict__ area) {
    const int b = blockIdx.x;
    const int r = b >> 2, q = b & 3;
    const int src = order[r];
    const vfloat4* __restrict__ row = (const vfloat4*)(masks + (size_t)src * HW) + q * 4096;
    unsigned* __restrict__ prow = packed + (size_t)r * WPR + q * 512;
    const int t = threadIdx.x;

    vfloat4 f[16];
    #pragma unroll
    for (int k = 0; k < 16; ++k)
        f[k] = __builtin_nontemporal_load(row + k * 256 + t);

    unsigned w0 = 0u, w1 = 0u;
    #pragma unroll
    for (int k = 0; k < 8; ++k) {
        const unsigned nib0 = (unsigned)(f[k][0] != 0.0f)        | ((unsigned)(f[k][1] != 0.0f) << 1)
                            | ((unsigned)(f[k][2] != 0.0f) << 2) | ((unsigned)(f[k][3] != 0.0f) << 3);
        w0 |= nib0 << (k * 4);
        const unsigned nib1 = (unsigned)(f[k + 8][0] != 0.0f)        | ((unsigned)(f[k + 8][1] != 0.0f) << 1)
                            | ((unsigned)(f[k + 8][2] != 0.0f) << 2) | ((unsigned)(f[k + 8][3] != 0.0f) << 3);
        w1 |= nib1 << (k * 4);
    }
    prow[t] = w0;
    prow[256 + t] = w1;

    int cnt = __builtin_popcount(w0) + __builtin_popcount(w1);
    for (int off = 32; off > 0; off >>= 1) cnt += __shfl_down(cnt, off, 64);
    __shared__ int red[4];
    const int lane = t & 63, w = t >> 6;
    if (lane == 0) red[w] = cnt;
    __syncthreads();
    if (t == 0) atomicAdd(area + r, (float)(red[0] + red[1] + red[2] + red[3]));
}

// ---------------- Kernel C: pairwise inter via i8 MFMA, LDS-free ----------------
// Block (p, kq): 128x128 tile pair p (I<=J), k-range = 128 packed words.
// 4 waves: quadrants (wr,wc) in {0,64}^2; each wave = 2x2 mfma_i32_32x32x32_i8
// tiles, full k-range. Per group of 4 k-steps: 4 uint4 per-lane loads from L2,
// register expansion, 16 MFMA. A-frag: row=lane&31, k-bytes=(lane>>5)*16+[0,16);
// Gram symmetry makes the B-frag identical in form. C/D: col=lane&31,
// row=(reg&3)+8*(reg>>2)+4*(lane>>5)  [guide §3, m74/m101].
__global__ __launch_bounds__(256, 3) void pair_kernel(const unsigned* __restrict__ packed,
                                                      int* __restrict__ partial) {
    const int p = blockIdx.x, kq = blockIdx.y;
    int I, J; tile_from_pair(p, I, J);
    const int A0 = I * 128, B0 = J * 128;
    const int t = threadIdx.x;
    const int wave = t >> 6, lane = t & 63, half = lane >> 5, lr = lane & 31;
    const int wr = (wave >> 1) * 64, wc = (wave & 1) * 64;

    // diagonal tile: quadrant rows 64..127 x cols 0..63 is entirely a>b -> unused
    if (I == J && wave == 2) return;

    const unsigned* __restrict__ rowA0 = packed + (size_t)(A0 + wr + lr) * WPR + kq * 128;
    const unsigned* __restrict__ rowA1 = rowA0 + 32 * WPR;
    const unsigned* __restrict__ rowB0 = packed + (size_t)(B0 + wc + lr) * WPR + kq * 128;
    const unsigned* __restrict__ rowB1 = rowB0 + 32 * WPR;
    const int sh = half * 16;

    v16i acc[2][2];
    #pragma unroll
    for (int i = 0; i < 2; ++i)
        #pragma unroll
        for (int j = 0; j < 2; ++j)
            #pragma unroll
            for (int r = 0; r < 16; ++r) acc[i][j][r] = 0;

    #pragma unroll 2
    for (int g = 0; g < 32; ++g) {
        const uint4 wa0 = *(const uint4*)(rowA0 + g * 4);
        const uint4 wa1 = *(const uint4*)(rowA1 + g * 4);
        const uint4 wb0 = *(const uint4*)(rowB0 + g * 4);
        const uint4 wb1 = *(const uint4*)(rowB1 + g * 4);
        const unsigned a0w[4] = { wa0.x, wa0.y, wa0.z, wa0.w };
        const unsigned a1w[4] = { wa1.x, wa1.y, wa1.z, wa1.w };
        const unsigned b0w[4] = { wb0.x, wb0.y, wb0.z, wb0.w };
        const unsigned b1w[4] = { wb1.x, wb1.y, wb1.z, wb1.w };
        #pragma unroll
        for (int w = 0; w < 4; ++w) {
            const v4i a0 = expand16(a0w[w], sh);
            const v4i a1 = expand16(a1w[w], sh);
            const v4i b0 = expand16(b0w[w], sh);
            const v4i b1 = expand16(b1w[w], sh);
            acc[0][0] = __builtin_amdgcn_mfma_i32_32x32x32_i8(a0, b0, acc[0][0], 0, 0, 0);
            acc[0][1] = __builtin_amdgcn_mfma_i32_32x32x32_i8(a0, b1, acc[0][1], 0, 0, 0);
            acc[1][0] = __builtin_amdgcn_mfma_i32_32x32x32_i8(a1, b0, acc[1][0], 0, 0, 0);
            acc[1][1] = __builtin_amdgcn_mfma_i32_32x32x32_i8(a1, b1, acc[1][1], 0, 0, 0);
        }
    }

    int* __restrict__ outp = partial + ((size_t)kq * NPAIRS + p) * 16384;
    #pragma unroll
    for (int i = 0; i < 2; ++i)
        #pragma unroll
        for (int j = 0; j < 2; ++j)
            #pragma unroll
            for (int reg = 0; reg < 16; ++reg) {
                const int m = wr + i * 32 + (reg & 3) + 8 * (reg >> 2) + 4 * half;
                const int n = wc + j * 32 + lr;
                outp[m * 128 + n] = acc[i][j][reg];
            }
}

// ---------------- Kernel D: combine partials + epilogue + column max ----------------
__global__ __launch_bounds__(256) void combine_kernel(const unsigned* __restrict__ partial,
                                                      const float* __restrict__ area,
                                                      unsigned* __restrict__ ioumax,
                                                      unsigned* __restrict__ innu,
                                                      unsigned* __restrict__ innl) {
    __shared__ unsigned redI[128], redU[128], redLB[128], redLA[8];
    __shared__ float aB[128];

    const int p = blockIdx.x, rg = blockIdx.y;
    int I, J; tile_from_pair(p, I, J);
    const int A0 = I * 128, B0 = J * 128;
    const int t = threadIdx.x;
    if (t < 128) { redI[t] = 0u; redU[t] = 0u; redLB[t] = 0u; aB[t] = area[B0 + t]; }
    if (t < 8) redLA[t] = 0u;
    __syncthreads();

    const int row = rg * 8 + (t >> 5);
    const int col = (t & 31) * 4;
    const int a = A0 + row;
    const float fa = area[a];

    unsigned sx = 0, sy = 0, sz = 0, sw = 0;
    #pragma unroll
    for (int kq = 0; kq < KQ; ++kq) {
        const uint4 v = *(const uint4*)(partial + ((size_t)kq * NPAIRS + p) * 16384 + row * 128 + col);
        sx += v.x; sy += v.y; sz += v.z; sw += v.w;
    }
    const unsigned sums[4] = { sx, sy, sz, sw };

    float mLA = 0.0f;
    #pragma unroll
    for (int j = 0; j < 4; ++j) {
        const int b = B0 + col + j;
        if (a > b) continue;
        const float inter = (float)sums[j];
        const float fb = aB[col + j];
        const float uni = (fb + fa) - inter;
        const float iou = inter / (uni + 1e-8f);
        const float ra = inter / (fa + 1e-8f);        // ratio_i (row a)
        const float rb = inter / (fb + 1e-8f);        // ratio_j (col b)
        const float v = __fsub_rn(1.0f, __fmul_rn(rb, ra));
        const float iab = (ra < 0.5f && rb >= 0.85f) ? v : 0.0f;
        const float iba = (rb < 0.5f && ra >= 0.85f) ? v : 0.0f;
        if (a < b) {
            atomicMax(&redI[col + j], __float_as_uint(iou));
            atomicMax(&redU[col + j], __float_as_uint(iab));   // inner[a,b] -> innu[b]
            mLA = fmaxf(mLA, iba);                             // inner[b,a] -> innl[a]
        }
        if (a == b - 1) atomicMax(&redLB[col + j], __float_as_uint(iab)); // superdiag -> innl[b]
    }
    atomicMax(&redLA[t >> 5], __float_as_uint(mLA));
    __syncthreads();
    if (t < 128) {
        atomicMax(&ioumax[B0 + t], redI[t]);
        atomicMax(&innu[B0 + t], redU[t]);
        atomicMax(&innl[B0 + t], redLB[t]);
    }
    if (t < 8) atomicMax(&innl[A0 + rg * 8 + t], redLA[t]);
}

// ---------------- Kernel E: final keep ----------------
__global__ __launch_bounds__(256) void keep_kernel(const float* __restrict__ ssort,
                                                   const unsigned* __restrict__ ioumax,
                                                   const unsigned* __restrict__ innu,
                                                   const unsigned* __restrict__ innl,
                                                   int* __restrict__ out_keep) {
    const int r = blockIdx.x * 256 + threadIdx.x;
    const float s0 = ssort[0];
    const bool conf = (s0 > 0.7f) ? (ssort[r] > 0.7f) : (r < 3);
    const bool keep = (__uint_as_float(ioumax[r]) <= 0.8f) && conf &&
                      (__uint_as_float(innu[r]) <= 0.5f) &&
                      (__uint_as_float(innl[r]) <= 0.5f);
    out_keep[r] = keep ? 1 : 0;
}

extern "C" void kernel_launch(void* const* d_in, const int* in_sizes, int n_in,
                              void* d_out, int out_size, void* d_ws, size_t ws_size,
                              hipStream_t stream) {
    const float* masks  = (const float*)d_in[0];
    const float* scores = (const float*)d_in[1];
    int* out = (int*)d_out;

    unsigned* packed  = (unsigned*)d_ws;                        // 8 MB
    unsigned* partial = packed + (size_t)N_MASKS * WPR;         // 16*36*16384 u32 = 37.75 MB
    unsigned* tail    = partial + (size_t)KQ * NPAIRS * 16384;
    int*      order   = (int*)tail;
    float*    ssort   = (float*)(order + N_MASKS);
    float*    area    = (float*)(ssort + N_MASKS);
    unsigned* ioumax  = (unsigned*)(area + N_MASKS);
    unsigned* innu    = ioumax + N_MASKS;
    unsigned* innl    = innu + N_MASKS;

    sort_kernel<<<8, 128, 0, stream>>>(scores, order, ssort, out, area, ioumax, innu, innl);
    pack_kernel<<<4096, 256, 0, stream>>>(masks, order, packed, area);
    pair_kernel<<<dim3(NPAIRS, KQ), 256, 0, stream>>>(packed, (int*)partial);
    combine_kernel<<<dim3(NPAIRS, KQ), 256, 0, stream>>>(partial, area, ioumax, innu, innl);
    keep_kernel<<<4, 256, 0, stream>>>(ssort, ioumax, innu, innl, out + N_MASKS);
}